// Round 7
// baseline (123.384 us; speedup 1.0000x reference)
//
#include <hip/hip_runtime.h>
#include <hip/hip_bf16.h>

typedef short s16x8 __attribute__((ext_vector_type(8)));
typedef float f32x4 __attribute__((ext_vector_type(4)));
typedef unsigned short u16x8 __attribute__((ext_vector_type(8)));

__device__ __forceinline__ unsigned short f2bf(float f) {
  union { __hip_bfloat16 h; unsigned short u; } cv;
  cv.h = __float2bfloat16(f);
  return cv.u;
}
__device__ __forceinline__ float bf2f(unsigned short u) {
  union { unsigned int i; float f; } cv;
  cv.i = ((unsigned int)u) << 16;
  return cv.f;
}

__device__ __forceinline__ void gload_lds16(const void* g, void* l) {
  __builtin_amdgcn_global_load_lds(
      (const __attribute__((address_space(1))) unsigned int*)g,
      (__attribute__((address_space(3))) unsigned int*)l,
      16, 0, 0);
}

// f32 -> bf16 cast of two buffers (Wk, Wq), float4-vectorized.
__global__ __launch_bounds__(256) void cast2_bf16(
    const float* __restrict__ a, unsigned short* __restrict__ da, int n4a,
    const float* __restrict__ b, unsigned short* __restrict__ db, int n4b) {
  const int total = n4a + n4b;
  for (int i = blockIdx.x * 256 + threadIdx.x; i < total; i += gridDim.x * 256) {
    const float* s; unsigned short* d; int j = i;
    if (j < n4a) { s = a; d = da; }
    else { j -= n4a; s = b; d = db; }
    float4 v = *(const float4*)(s + (size_t)j * 4);
    ushort4 o;
    o.x = f2bf(v.x); o.y = f2bf(v.y); o.z = f2bf(v.z); o.w = f2bf(v.w);
    *(ushort4*)(d + (size_t)j * 4) = o;
  }
}

// Per-batch compaction scan: keep[l] = (mask[l]==0).
__global__ __launch_bounds__(256) void mask_scan(
    const int* __restrict__ mask, int* __restrict__ idx,
    int* __restrict__ Lc, int* __restrict__ Lcp) {
  const int b = blockIdx.x;
  const int* mb = mask + (size_t)b * 2048;
  int* ib = idx + (size_t)b * 2048;
  const int t = threadIdx.x;
  __shared__ int tot[256];
  __shared__ int off[257];
  int keep[8], cnt = 0;
#pragma unroll
  for (int j = 0; j < 8; ++j) {
    keep[j] = (mb[t * 8 + j] == 0);
    cnt += keep[j];
  }
  tot[t] = cnt;
  __syncthreads();
  if (t == 0) {
    int s = 0;
    for (int i = 0; i < 256; ++i) { off[i] = s; s += tot[i]; }
    off[256] = s;
  }
  __syncthreads();
  int p = off[t];
#pragma unroll
  for (int j = 0; j < 8; ++j)
    if (keep[j]) ib[p++] = t * 8 + j;
  if (t == 0) {
    Lc[b] = off[256];
    Lcp[b] = (off[256] + 127) & ~127;
  }
}

// Gather unmasked H rows (f32) -> Hc (B, L, Dh) bf16 row-major AND
// HcT (B, Dh, L) bf16 transposed. Rows [Lc, Lcp) zero-filled.
__global__ __launch_bounds__(256) void gather_cast(
    const float* __restrict__ H, const int* __restrict__ idx,
    const int* __restrict__ Lc, const int* __restrict__ Lcp,
    unsigned short* __restrict__ Hc, unsigned short* __restrict__ HcT) {
  const int b = blockIdx.z;
  const int j0 = blockIdx.x * 64, d0 = blockIdx.y * 64;
  if (j0 >= Lcp[b]) return;
  const int lc = Lc[b];
  __shared__ unsigned short tile[64][72];
  const int t = threadIdx.x;

  const int r = t >> 2, dc = (t & 3) * 16;
  const int j = j0 + r;
  const int src = (j < lc) ? idx[(size_t)b * 2048 + j] : -1;
  ushort4 s[4];
  if (src >= 0) {
    const float* p = H + ((size_t)b * 2048 + src) * 1024 + d0 + dc;
#pragma unroll
    for (int i = 0; i < 4; ++i) {
      float4 v = *(const float4*)(p + 4 * i);
      s[i].x = f2bf(v.x); s[i].y = f2bf(v.y); s[i].z = f2bf(v.z); s[i].w = f2bf(v.w);
    }
  } else {
#pragma unroll
    for (int i = 0; i < 4; ++i) { s[i].x = 0; s[i].y = 0; s[i].z = 0; s[i].w = 0; }
  }
  unsigned short* hcrow = Hc + ((size_t)b * 2048 + j) * 1024 + d0 + dc;
#pragma unroll
  for (int i = 0; i < 4; ++i) {
    *(ushort4*)&tile[r][dc + 4 * i] = s[i];
    *(ushort4*)(hcrow + 4 * i) = s[i];
  }
  __syncthreads();

  const int dr = t >> 2, lcc = (t & 3) * 16;
  unsigned short o[16];
#pragma unroll
  for (int i = 0; i < 16; ++i) o[i] = tile[lcc + i][dr];
  unsigned short* dst = HcT + ((size_t)b * 1024 + d0 + dr) * 2048 + j0 + lcc;
  *(uint4*)dst = *(uint4*)&o[0];
  *(uint4*)(dst + 8) = *(uint4*)&o[8];
}

// C (M x N tile 128 x BN) = A (M x K) * B^T, double-buffered 2-phase K-loop.
// A_F32: A is f32, reg-staged with cast (pipelined: load -> compute -> write).
// else A is bf16 via global_load_lds. B always bf16 via global_load_lds.
// MODE 0: plain 3D grid. MODE 1: batched XCD-chunk swizzle (batch = flat&7).
// MODE 2: single-matrix XCD-chunk swizzle.
template <int BN, bool OUT_BF16, int MODE, int NBN, bool A_F32>
__global__ __launch_bounds__(256) void gemm_bt(
    const void* __restrict__ Ag_, const unsigned short* __restrict__ Bg,
    void* __restrict__ Cg_, int N, int Kfix, int lda, int ldb, float scale,
    long long strideA, long long strideB, long long strideC,
    const int* __restrict__ mExt, const int* __restrict__ nExt,
    const int* __restrict__ kDyn) {
  int b, bm, bn;
  if constexpr (MODE == 0) {
    b = blockIdx.z; bm = blockIdx.y; bn = blockIdx.x;
  } else if constexpr (MODE == 1) {
    b = blockIdx.x & 7;
    const int inner = blockIdx.x >> 3;
    bm = inner / NBN; bn = inner % NBN;
  } else {
    const int cs = gridDim.x >> 3;
    const int logical = (blockIdx.x & 7) * cs + (blockIdx.x >> 3);
    b = 0; bm = logical / NBN; bn = logical % NBN;
  }
  if (mExt && bm * 128 >= mExt[b]) return;
  if (nExt && bn * BN >= nExt[b]) return;
  const int K = kDyn ? kDyn[b] : Kfix;

  constexpr int NF = BN / 32;        // B fragments per wave
  __shared__ unsigned short As[2][128 * 32];
  __shared__ unsigned short Bs[2][BN * 32];
  const int tid = threadIdx.x;
  const int l = tid & 63, wid = tid >> 6;
  const int wr = wid >> 1, wc = wid & 1;

  const unsigned short* Bbf = Bg + (size_t)b * strideB;
  const int rowA0 = bm * 128, rowB0 = bn * BN;

  const unsigned short* Abf = nullptr;
  const float* aBase = nullptr;
  if constexpr (A_F32)
    aBase = (const float*)Ag_ + (size_t)b * strideA +
            (size_t)(rowA0 + (tid >> 1)) * lda + (tid & 1) * 16;
  else
    Abf = (const unsigned short*)Ag_ + (size_t)b * strideA;

  f32x4 acc[4][NF] = {};

  const size_t aOff = A_F32 ? 0 :
      (size_t)(rowA0 + (wid * 2) * 16 + (l >> 2)) * lda + (l & 3) * 8;
  const size_t bOff =
      (size_t)(rowB0 + ((BN == 128 ? wid * 2 : wid)) * 16 + (l >> 2)) * ldb + (l & 3) * 8;

  float4 ar[4];  // A_F32 staging registers (16 f32 per thread)

  auto loadA = [&](int k0) {
    if constexpr (A_F32) {
#pragma unroll
      for (int i = 0; i < 4; ++i)
        ar[i] = *(const float4*)(aBase + k0 + 4 * i);
    }
  };
  auto writeA = [&](int buf) {
    if constexpr (A_F32) {
      ushort4 s[4];
#pragma unroll
      for (int i = 0; i < 4; ++i) {
        s[i].x = f2bf(ar[i].x); s[i].y = f2bf(ar[i].y);
        s[i].z = f2bf(ar[i].z); s[i].w = f2bf(ar[i].w);
      }
      unsigned short* dst = &As[buf][(tid >> 1) * 32 + (tid & 1) * 16];
      *(ushort4*)(dst + 0) = s[0];
      *(ushort4*)(dst + 4) = s[1];
      *(ushort4*)(dst + 8) = s[2];
      *(ushort4*)(dst + 12) = s[3];
    }
  };
  auto stage = [&](int buf, int k0) {
    if constexpr (!A_F32) {
#pragma unroll
      for (int i = 0; i < 2; ++i)
        gload_lds16(Abf + aOff + (size_t)i * 16 * lda + k0, &As[buf][(wid * 2 + i) * 512]);
    }
    if constexpr (BN == 128) {
#pragma unroll
      for (int i = 0; i < 2; ++i)
        gload_lds16(Bbf + bOff + (size_t)i * 16 * ldb + k0, &Bs[buf][(wid * 2 + i) * 512]);
    } else {
      gload_lds16(Bbf + bOff + k0, &Bs[buf][wid * 512]);
    }
  };
  auto compute = [&](int buf) {
    s16x8 af[4], bfr[NF];
#pragma unroll
    for (int m = 0; m < 4; ++m)
      af[m] = *(const s16x8*)&As[buf][(wr * 64 + m * 16 + (l & 15)) * 32 + (l >> 4) * 8];
#pragma unroll
    for (int n = 0; n < NF; ++n)
      bfr[n] = *(const s16x8*)&Bs[buf][(wc * (BN / 2) + n * 16 + (l & 15)) * 32 + (l >> 4) * 8];
#pragma unroll
    for (int m = 0; m < 4; ++m)
#pragma unroll
      for (int n = 0; n < NF; ++n)
        acc[m][n] = __builtin_amdgcn_mfma_f32_16x16x32_bf16(af[m], bfr[n], acc[m][n], 0, 0, 0);
  };

  loadA(0);
  stage(0, 0);
  writeA(0);
  __syncthreads();
  int cur = 0;
  for (int k0 = 32; k0 < K; k0 += 32) {
    loadA(k0);            // issue next A loads (A_F32 path)
    stage(cur ^ 1, k0);   // issue next-tile gload_lds
    compute(cur);         // MFMA on current (hides load latency)
    writeA(cur ^ 1);      // convert + ds_write next A (A_F32 path)
    __syncthreads();
    cur ^= 1;
  }
  compute(cur);

  const int crow0 = bm * 128 + wr * 64, ccol0 = bn * BN + wc * (BN / 2);
  unsigned short* Cst = nullptr;
  float* Cf = nullptr;
  if constexpr (OUT_BF16)
    Cst = (unsigned short*)Cg_ + (size_t)b * strideC;
  else
    Cf = (float*)Cg_ + (size_t)b * strideC;
#pragma unroll
  for (int m = 0; m < 4; ++m) {
#pragma unroll
    for (int n = 0; n < NF; ++n) {
#pragma unroll
      for (int r = 0; r < 4; ++r) {
        const int row = crow0 + m * 16 + ((l >> 4) << 2) + r;
        const int col = ccol0 + n * 16 + (l & 15);
        const float val = acc[m][n][r] * scale;
        if constexpr (OUT_BF16)
          Cst[(size_t)row * N + col] = f2bf(val);
        else
          Cf[(size_t)row * N + col] = val;
      }
    }
  }
}

// Softmax over compacted cols [0, Lc); cols [Lc, Lcp) get exact 0.
__global__ __launch_bounds__(256) void softmax_c(
    unsigned short* __restrict__ S, const int* __restrict__ Lc,
    const int* __restrict__ Lcp) {
  const int row = blockIdx.x;  // b*T + t, T=1024
  const int b = row >> 10;
  unsigned short* Sr = S + (size_t)row * 2048;
  const int lc = Lc[b], lcp = Lcp[b];
  const int t = threadIdx.x;
  const int j0 = t * 8;
  const bool act = j0 < lcp;

  float v[8];
  if (act) {
    u16x8 raw = *(const u16x8*)(Sr + j0);
#pragma unroll
    for (int j = 0; j < 8; ++j) v[j] = (j0 + j < lc) ? bf2f(raw[j]) : -1.0e30f;
  } else {
#pragma unroll
    for (int j = 0; j < 8; ++j) v[j] = -1.0e30f;
  }

  float mx = -3.0e38f;
#pragma unroll
  for (int j = 0; j < 8; ++j) mx = fmaxf(mx, v[j]);
#pragma unroll
  for (int off = 32; off; off >>= 1) mx = fmaxf(mx, __shfl_xor(mx, off));
  __shared__ float redmx[4];
  __shared__ float redsm[4];
  if ((t & 63) == 0) redmx[t >> 6] = mx;
  __syncthreads();
  mx = fmaxf(fmaxf(redmx[0], redmx[1]), fmaxf(redmx[2], redmx[3]));

  float s = 0.f;
#pragma unroll
  for (int j = 0; j < 8; ++j) {
    v[j] = __expf(v[j] - mx);
    s += v[j];
  }
#pragma unroll
  for (int off = 32; off; off >>= 1) s += __shfl_xor(s, off);
  if ((t & 63) == 0) redsm[t >> 6] = s;
  __syncthreads();
  s = redsm[0] + redsm[1] + redsm[2] + redsm[3];
  const float inv = 1.0f / s;

  if (act) {
    u16x8 o;
#pragma unroll
    for (int j = 0; j < 8; ++j) o[j] = f2bf(v[j] * inv);
    *(u16x8*)(Sr + j0) = o;
  }
}

extern "C" void kernel_launch(void* const* d_in, const int* in_sizes, int n_in,
                              void* d_out, int out_size, void* d_ws, size_t ws_size,
                              hipStream_t stream) {
  const float* H  = (const float*)d_in[0];   // (B, L, Dh)
  const float* G  = (const float*)d_in[1];   // (B, T, Dg)
  const int* mask = (const int*)d_in[2];     // (B, L), nonzero = masked
  const float* Wk = (const float*)d_in[3];   // (P, Dh)
  const float* Wq = (const float*)d_in[4];   // (P, Dg)
  float* Z = (float*)d_out;                  // (B, T, Dh)

  const float SCALE = 0.0625f;  // 256^-0.5
  const size_t MiB = 1024 * 1024;

  char* ws = (char*)d_ws;
  unsigned short* HcT  = (unsigned short*)(ws);             // (B, Dh, L)  32 MiB
  unsigned short* Hc   = (unsigned short*)(ws + 32 * MiB);  // (B, L, Dh)  32 MiB
  unsigned short* Sbuf = Hc;  // alias: Hc dead after Kproj
  unsigned short* Kc   = (unsigned short*)(ws + 64 * MiB);  // (B, L, P)    8 MiB
  unsigned short* Qbuf = (unsigned short*)(ws + 72 * MiB);  // (B, T, P)    4 MiB
  int* idx = (int*)Qbuf;      // alias: idx dead before Qproj writes
  int* Lc  = (int*)(ws + 76 * MiB);
  int* Lcp = Lc + 16;
  unsigned short* Wkbf = (unsigned short*)(ws + 89 * MiB);  // 0.5 MiB
  unsigned short* Wqbf = (unsigned short*)(ws + 90 * MiB);  // 0.375 MiB

  // 0) scan + weight casts
  mask_scan<<<dim3(8), 256, 0, stream>>>(mask, idx, Lc, Lcp);
  cast2_bf16<<<dim3(128), 256, 0, stream>>>(
      Wk, Wkbf, 256 * 1024 / 4, Wq, Wqbf, 256 * 768 / 4);

  // 1) gather unmasked H rows -> Hc + HcT (bf16), zero pad
  gather_cast<<<dim3(32, 16, 8), 256, 0, stream>>>(H, idx, Lc, Lcp, Hc, HcT);

  // 2) Kc = Hc @ Wk^T  (per batch: M = Lcp[b], N = 256, K = 1024)
  //    batched swizzle: NBM=16, NBN=4 -> 512 blocks
  gemm_bt<64, true, 1, 4, false><<<dim3(512), 256, 0, stream>>>(
      Hc, Wkbf, Kc, 256, 1024, 1024, 1024, 1.0f,
      (long long)2048 * 1024, 0, (long long)2048 * 256, Lcp, nullptr, nullptr);

  // 3) Q = G @ Wq^T  (M = 8192, N = 256, K = 768); A = G f32 reg-staged
  gemm_bt<64, true, 2, 4, true><<<dim3(256), 256, 0, stream>>>(
      G, Wqbf, Qbuf, 256, 768, 768, 768, 1.0f, 0, 0, 0,
      nullptr, nullptr, nullptr);

  // 4) S = Q @ Kc^T * SCALE  (per batch: M = 1024, N = Lcp[b], K = 256)
  //    batched swizzle: NBM=8, NBN=16 -> 1024 blocks
  gemm_bt<128, true, 1, 16, false><<<dim3(1024), 256, 0, stream>>>(
      Qbuf, Kc, Sbuf, 2048, 256, 256, 256, SCALE,
      (long long)1024 * 256, (long long)2048 * 256, (long long)1024 * 2048,
      nullptr, Lcp, nullptr);

  // 5) softmax over compacted cols, in place
  softmax_c<<<dim3(8 * 1024), 256, 0, stream>>>(Sbuf, Lc, Lcp);

  // 6) Z = alpha @ Hc  (per batch: M = 1024, N = 1024, K = Lcp[b])
  //    128x64 tiles + dbuf: NBM=8, NBN=16 -> 1024 blocks (4 blocks/CU)
  gemm_bt<64, false, 1, 16, false><<<dim3(1024), 256, 0, stream>>>(
      Sbuf, HcT, Z, 1024, 0, 2048, 2048, 1.0f,
      (long long)1024 * 2048, (long long)1024 * 2048, (long long)1024 * 1024,
      nullptr, nullptr, Lcp);
}

// Round 8
// 115.855 us; speedup vs baseline: 1.0650x; 1.0650x over previous
//
#include <hip/hip_runtime.h>
#include <hip/hip_bf16.h>

typedef short s16x8 __attribute__((ext_vector_type(8)));
typedef float f32x4 __attribute__((ext_vector_type(4)));
typedef unsigned short u16x8 __attribute__((ext_vector_type(8)));

__device__ __forceinline__ unsigned short f2bf(float f) {
  union { __hip_bfloat16 h; unsigned short u; } cv;
  cv.h = __float2bfloat16(f);
  return cv.u;
}
__device__ __forceinline__ float bf2f(unsigned short u) {
  union { unsigned int i; float f; } cv;
  cv.i = ((unsigned int)u) << 16;
  return cv.f;
}

__device__ __forceinline__ void gload_lds16(const void* g, void* l) {
  __builtin_amdgcn_global_load_lds(
      (const __attribute__((address_space(1))) unsigned int*)g,
      (__attribute__((address_space(3))) unsigned int*)l,
      16, 0, 0);
}

// One-shot f32->bf16 cast of three buffers (G, Wk, Wq), float4-vectorized.
__global__ __launch_bounds__(256) void cast3_bf16(
    const float* __restrict__ a, unsigned short* __restrict__ da, int n4a,
    const float* __restrict__ b, unsigned short* __restrict__ db, int n4b,
    const float* __restrict__ c, unsigned short* __restrict__ dc, int n4c) {
  const int total = n4a + n4b + n4c;
  for (int i = blockIdx.x * 256 + threadIdx.x; i < total; i += gridDim.x * 256) {
    const float* s; unsigned short* d; int j = i;
    if (j < n4a) { s = a; d = da; }
    else if ((j -= n4a) < n4b) { s = b; d = db; }
    else { j -= n4b; s = c; d = dc; }
    float4 v = *(const float4*)(s + (size_t)j * 4);
    ushort4 o;
    o.x = f2bf(v.x); o.y = f2bf(v.y); o.z = f2bf(v.z); o.w = f2bf(v.w);
    *(ushort4*)(d + (size_t)j * 4) = o;
  }
}

// Per-batch compaction scan: keep[l] = (mask[l]==0).
__global__ __launch_bounds__(256) void mask_scan(
    const int* __restrict__ mask, int* __restrict__ idx,
    int* __restrict__ Lc, int* __restrict__ Lcp) {
  const int b = blockIdx.x;
  const int* mb = mask + (size_t)b * 2048;
  int* ib = idx + (size_t)b * 2048;
  const int t = threadIdx.x;
  __shared__ int tot[256];
  __shared__ int off[257];
  int keep[8], cnt = 0;
#pragma unroll
  for (int j = 0; j < 8; ++j) {
    keep[j] = (mb[t * 8 + j] == 0);
    cnt += keep[j];
  }
  tot[t] = cnt;
  __syncthreads();
  if (t == 0) {
    int s = 0;
    for (int i = 0; i < 256; ++i) { off[i] = s; s += tot[i]; }
    off[256] = s;
  }
  __syncthreads();
  int p = off[t];
#pragma unroll
  for (int j = 0; j < 8; ++j)
    if (keep[j]) ib[p++] = t * 8 + j;
  if (t == 0) {
    Lc[b] = off[256];
    Lcp[b] = (off[256] + 127) & ~127;
  }
}

// Gather unmasked H rows (f32) -> Hc (B, L, Dh) bf16 row-major AND
// HcT (B, Dh, L) bf16 transposed. Rows [Lc, Lcp) zero-filled.
__global__ __launch_bounds__(256) void gather_cast(
    const float* __restrict__ H, const int* __restrict__ idx,
    const int* __restrict__ Lc, const int* __restrict__ Lcp,
    unsigned short* __restrict__ Hc, unsigned short* __restrict__ HcT) {
  const int b = blockIdx.z;
  const int j0 = blockIdx.x * 64, d0 = blockIdx.y * 64;
  if (j0 >= Lcp[b]) return;
  const int lc = Lc[b];
  __shared__ unsigned short tile[64][72];
  const int t = threadIdx.x;

  const int r = t >> 2, dc = (t & 3) * 16;
  const int j = j0 + r;
  const int src = (j < lc) ? idx[(size_t)b * 2048 + j] : -1;
  ushort4 s[4];
  if (src >= 0) {
    const float* p = H + ((size_t)b * 2048 + src) * 1024 + d0 + dc;
#pragma unroll
    for (int i = 0; i < 4; ++i) {
      float4 v = *(const float4*)(p + 4 * i);
      s[i].x = f2bf(v.x); s[i].y = f2bf(v.y); s[i].z = f2bf(v.z); s[i].w = f2bf(v.w);
    }
  } else {
#pragma unroll
    for (int i = 0; i < 4; ++i) { s[i].x = 0; s[i].y = 0; s[i].z = 0; s[i].w = 0; }
  }
  unsigned short* hcrow = Hc + ((size_t)b * 2048 + j) * 1024 + d0 + dc;
#pragma unroll
  for (int i = 0; i < 4; ++i) {
    *(ushort4*)&tile[r][dc + 4 * i] = s[i];
    *(ushort4*)(hcrow + 4 * i) = s[i];
  }
  __syncthreads();

  const int dr = t >> 2, lcc = (t & 3) * 16;
  unsigned short o[16];
#pragma unroll
  for (int i = 0; i < 16; ++i) o[i] = tile[lcc + i][dr];
  unsigned short* dst = HcT + ((size_t)b * 1024 + d0 + dr) * 2048 + j0 + lcc;
  *(uint4*)dst = *(uint4*)&o[0];
  *(uint4*)(dst + 8) = *(uint4*)&o[8];
}

// C (M x N tile 128 x BN) = A (M x K) * B^T, bf16 via global_load_lds.
// BK = 64. LDS rows are 128 B; to avoid the stride-128B bank conflict the
// 16B slots within each row are XOR-permuted by (row&7): the global SOURCE
// slot is pre-swizzled (LDS dest stays linear, coalescing preserved: each
// 8-lane group reads one permuted contiguous 128 B run), and fragment reads
// apply the same XOR. Net bank aliasing: 2-way (free).
// MODE 0: plain 3D grid. MODE 1: batched XCD-chunk swizzle (batch = flat&7).
// MODE 2: single-matrix XCD-chunk swizzle.
template <int BN, bool OUT_BF16, int MODE, int NBN>
__global__ __launch_bounds__(256) void gemm_bt(
    const unsigned short* __restrict__ Ag, const unsigned short* __restrict__ Bg,
    void* __restrict__ Cg_, int N, int Kfix, int lda, int ldb, float scale,
    long long strideA, long long strideB, long long strideC,
    const int* __restrict__ mExt, const int* __restrict__ nExt,
    const int* __restrict__ kDyn) {
  int b, bm, bn;
  if constexpr (MODE == 0) {
    b = blockIdx.z; bm = blockIdx.y; bn = blockIdx.x;
  } else if constexpr (MODE == 1) {
    b = blockIdx.x & 7;
    const int inner = blockIdx.x >> 3;
    bm = inner / NBN; bn = inner % NBN;
  } else {
    const int cs = gridDim.x >> 3;
    const int logical = (blockIdx.x & 7) * cs + (blockIdx.x >> 3);
    b = 0; bm = logical / NBN; bn = logical % NBN;
  }
  if (mExt && bm * 128 >= mExt[b]) return;
  if (nExt && bn * BN >= nExt[b]) return;
  const int K = kDyn ? kDyn[b] : Kfix;

  constexpr int NF = BN / 32;        // B fragments per wave
  __shared__ unsigned short As[128 * 64];
  __shared__ unsigned short Bs[BN * 64];
  const int tid = threadIdx.x;
  const int l = tid & 63, wid = tid >> 6;
  const int wr = wid >> 1, wc = wid & 1;

  const unsigned short* Abf = Ag + (size_t)b * strideA;
  const unsigned short* Bbf = Bg + (size_t)b * strideB;
  const int rowA0 = bm * 128, rowB0 = bn * BN;

  // Staging lane decode: chunk = 8 rows x 8 slots of 16 B (1 KiB).
  const int srow = l >> 3;                   // row within chunk
  const int sslot = (l & 7) ^ (srow & 7);    // pre-swizzled global 16B slot
  const int soff = sslot * 8;                // shorts

  f32x4 acc[4][NF] = {};

  for (int k0 = 0; k0 < K; k0 += 64) {
    // A: 16 chunks, 4 per wave.
#pragma unroll
    for (int i = 0; i < 4; ++i) {
      const int c = wid * 4 + i;
      gload_lds16(Abf + (size_t)(rowA0 + c * 8 + srow) * lda + k0 + soff,
                  &As[c * 512]);
    }
    // B: BN/8 chunks; 4 per wave (BN=128) or 2 (BN=64).
#pragma unroll
    for (int i = 0; i < BN / 32; ++i) {
      const int c = wid * (BN / 32) + i;
      gload_lds16(Bbf + (size_t)(rowB0 + c * 8 + srow) * ldb + k0 + soff,
                  &Bs[c * 512]);
    }
    __syncthreads();

    s16x8 af[4][2], bfr[NF][2];
#pragma unroll
    for (int m = 0; m < 4; ++m) {
      const int row = wr * 64 + m * 16 + (l & 15);
      const int rx = row & 7;
#pragma unroll
      for (int kk = 0; kk < 2; ++kk) {
        const int slot = kk * 4 + (l >> 4);
        af[m][kk] = *(const s16x8*)&As[row * 64 + (slot ^ rx) * 8];
      }
    }
#pragma unroll
    for (int n = 0; n < NF; ++n) {
      const int row = wc * (BN / 2) + n * 16 + (l & 15);
      const int rx = row & 7;
#pragma unroll
      for (int kk = 0; kk < 2; ++kk) {
        const int slot = kk * 4 + (l >> 4);
        bfr[n][kk] = *(const s16x8*)&Bs[row * 64 + (slot ^ rx) * 8];
      }
    }
#pragma unroll
    for (int kk = 0; kk < 2; ++kk)
#pragma unroll
      for (int m = 0; m < 4; ++m)
#pragma unroll
        for (int n = 0; n < NF; ++n)
          acc[m][n] = __builtin_amdgcn_mfma_f32_16x16x32_bf16(
              af[m][kk], bfr[n][kk], acc[m][n], 0, 0, 0);
    __syncthreads();
  }

  const int crow0 = bm * 128 + wr * 64, ccol0 = bn * BN + wc * (BN / 2);
  unsigned short* Cst = nullptr;
  float* Cf = nullptr;
  if constexpr (OUT_BF16)
    Cst = (unsigned short*)Cg_ + (size_t)b * strideC;
  else
    Cf = (float*)Cg_ + (size_t)b * strideC;
#pragma unroll
  for (int m = 0; m < 4; ++m) {
#pragma unroll
    for (int n = 0; n < NF; ++n) {
#pragma unroll
      for (int r = 0; r < 4; ++r) {
        const int row = crow0 + m * 16 + ((l >> 4) << 2) + r;
        const int col = ccol0 + n * 16 + (l & 15);
        const float val = acc[m][n][r] * scale;
        if constexpr (OUT_BF16)
          Cst[(size_t)row * N + col] = f2bf(val);
        else
          Cf[(size_t)row * N + col] = val;
      }
    }
  }
}

// Softmax over compacted cols [0, Lc); cols [Lc, Lcp) get exact 0.
__global__ __launch_bounds__(256) void softmax_c(
    unsigned short* __restrict__ S, const int* __restrict__ Lc,
    const int* __restrict__ Lcp) {
  const int row = blockIdx.x;  // b*T + t, T=1024
  const int b = row >> 10;
  unsigned short* Sr = S + (size_t)row * 2048;
  const int lc = Lc[b], lcp = Lcp[b];
  const int t = threadIdx.x;
  const int j0 = t * 8;
  const bool act = j0 < lcp;

  float v[8];
  if (act) {
    u16x8 raw = *(const u16x8*)(Sr + j0);
#pragma unroll
    for (int j = 0; j < 8; ++j) v[j] = (j0 + j < lc) ? bf2f(raw[j]) : -1.0e30f;
  } else {
#pragma unroll
    for (int j = 0; j < 8; ++j) v[j] = -1.0e30f;
  }

  float mx = -3.0e38f;
#pragma unroll
  for (int j = 0; j < 8; ++j) mx = fmaxf(mx, v[j]);
#pragma unroll
  for (int off = 32; off; off >>= 1) mx = fmaxf(mx, __shfl_xor(mx, off));
  __shared__ float redmx[4];
  __shared__ float redsm[4];
  if ((t & 63) == 0) redmx[t >> 6] = mx;
  __syncthreads();
  mx = fmaxf(fmaxf(redmx[0], redmx[1]), fmaxf(redmx[2], redmx[3]));

  float s = 0.f;
#pragma unroll
  for (int j = 0; j < 8; ++j) {
    v[j] = __expf(v[j] - mx);
    s += v[j];
  }
#pragma unroll
  for (int off = 32; off; off >>= 1) s += __shfl_xor(s, off);
  if ((t & 63) == 0) redsm[t >> 6] = s;
  __syncthreads();
  s = redsm[0] + redsm[1] + redsm[2] + redsm[3];
  const float inv = 1.0f / s;

  if (act) {
    u16x8 o;
#pragma unroll
    for (int j = 0; j < 8; ++j) o[j] = f2bf(v[j] * inv);
    *(u16x8*)(Sr + j0) = o;
  }
}

extern "C" void kernel_launch(void* const* d_in, const int* in_sizes, int n_in,
                              void* d_out, int out_size, void* d_ws, size_t ws_size,
                              hipStream_t stream) {
  const float* H  = (const float*)d_in[0];   // (B, L, Dh)
  const float* G  = (const float*)d_in[1];   // (B, T, Dg)
  const int* mask = (const int*)d_in[2];     // (B, L), nonzero = masked
  const float* Wk = (const float*)d_in[3];   // (P, Dh)
  const float* Wq = (const float*)d_in[4];   // (P, Dg)
  float* Z = (float*)d_out;                  // (B, T, Dh)

  const float SCALE = 0.0625f;  // 256^-0.5
  const size_t MiB = 1024 * 1024;

  char* ws = (char*)d_ws;
  unsigned short* HcT  = (unsigned short*)(ws);             // (B, Dh, L)  32 MiB
  unsigned short* Hc   = (unsigned short*)(ws + 32 * MiB);  // (B, L, Dh)  32 MiB
  unsigned short* Sbuf = Hc;  // alias: Hc dead after Kproj
  unsigned short* Kc   = (unsigned short*)(ws + 64 * MiB);  // (B, L, P)    8 MiB
  unsigned short* Qbuf = (unsigned short*)(ws + 72 * MiB);  // (B, T, P)    4 MiB
  int* idx = (int*)Qbuf;      // alias: idx dead before Qproj writes
  int* Lc  = (int*)(ws + 76 * MiB);
  int* Lcp = Lc + 16;
  unsigned short* Gbf  = (unsigned short*)(ws + 76 * MiB + 4096);  // 12 MiB
  unsigned short* Wkbf = (unsigned short*)(ws + 89 * MiB);         // 0.5 MiB
  unsigned short* Wqbf = (unsigned short*)(ws + 90 * MiB);         // 0.375 MiB

  // 0) scan + casts
  mask_scan<<<dim3(8), 256, 0, stream>>>(mask, idx, Lc, Lcp);
  cast3_bf16<<<dim3(1024), 256, 0, stream>>>(
      G, Gbf, 8 * 1024 * 768 / 4, Wk, Wkbf, 256 * 1024 / 4, Wq, Wqbf, 256 * 768 / 4);

  // 1) gather unmasked H rows -> Hc + HcT (bf16), zero pad
  gather_cast<<<dim3(32, 16, 8), 256, 0, stream>>>(H, idx, Lc, Lcp, Hc, HcT);

  // 2) Kc = Hc @ Wk^T  (per batch: M = Lcp[b], N = 256, K = 1024)
  //    batched swizzle: NBM=16, NBN=4 -> 512 blocks
  gemm_bt<64, true, 1, 4><<<dim3(512), 256, 0, stream>>>(
      Hc, Wkbf, Kc, 256, 1024, 1024, 1024, 1.0f,
      (long long)2048 * 1024, 0, (long long)2048 * 256, Lcp, nullptr, nullptr);

  // 3) Q = G @ Wq^T  (M = 8192, N = 256, K = 768); single swizzle NBM=64 NBN=4
  gemm_bt<64, true, 2, 4><<<dim3(256), 256, 0, stream>>>(
      Gbf, Wqbf, Qbuf, 256, 768, 768, 768, 1.0f, 0, 0, 0,
      nullptr, nullptr, nullptr);

  // 4) S = Q @ Kc^T * SCALE  (per batch: M = 1024, N = Lcp[b], K = 256)
  //    batched swizzle: NBM=8, NBN=16 -> 1024 blocks
  gemm_bt<128, true, 1, 16><<<dim3(1024), 256, 0, stream>>>(
      Qbuf, Kc, Sbuf, 2048, 256, 256, 256, SCALE,
      (long long)1024 * 256, (long long)2048 * 256, (long long)1024 * 2048,
      nullptr, Lcp, nullptr);

  // 5) softmax over compacted cols, in place
  softmax_c<<<dim3(8 * 1024), 256, 0, stream>>>(Sbuf, Lc, Lcp);

  // 6) Z = alpha @ Hc  (per batch: M = 1024, N = 1024, K = Lcp[b])
  //    128x128 tiles: NBM=8, NBN=8 -> 512 blocks
  gemm_bt<128, false, 1, 8><<<dim3(512), 256, 0, stream>>>(
      Sbuf, HcT, Z, 1024, 0, 2048, 2048, 1.0f,
      (long long)1024 * 2048, (long long)1024 * 2048, (long long)1024 * 1024,
      nullptr, nullptr, Lcp);
}

// Round 9
// 110.590 us; speedup vs baseline: 1.1157x; 1.0476x over previous
//
#include <hip/hip_runtime.h>
#include <hip/hip_bf16.h>

typedef short s16x8 __attribute__((ext_vector_type(8)));
typedef float f32x4 __attribute__((ext_vector_type(4)));
typedef unsigned short u16x8 __attribute__((ext_vector_type(8)));

__device__ __forceinline__ unsigned short f2bf(float f) {
  union { __hip_bfloat16 h; unsigned short u; } cv;
  cv.h = __float2bfloat16(f);
  return cv.u;
}
__device__ __forceinline__ float bf2f(unsigned short u) {
  union { unsigned int i; float f; } cv;
  cv.i = ((unsigned int)u) << 16;
  return cv.f;
}

__device__ __forceinline__ void gload_lds16(const void* g, void* l) {
  __builtin_amdgcn_global_load_lds(
      (const __attribute__((address_space(1))) unsigned int*)g,
      (__attribute__((address_space(3))) unsigned int*)l,
      16, 0, 0);
}

// One-shot f32->bf16 cast of three buffers (G, Wk, Wq), float4-vectorized.
__global__ __launch_bounds__(256) void cast3_bf16(
    const float* __restrict__ a, unsigned short* __restrict__ da, int n4a,
    const float* __restrict__ b, unsigned short* __restrict__ db, int n4b,
    const float* __restrict__ c, unsigned short* __restrict__ dc, int n4c) {
  const int total = n4a + n4b + n4c;
  for (int i = blockIdx.x * 256 + threadIdx.x; i < total; i += gridDim.x * 256) {
    const float* s; unsigned short* d; int j = i;
    if (j < n4a) { s = a; d = da; }
    else if ((j -= n4a) < n4b) { s = b; d = db; }
    else { j -= n4b; s = c; d = dc; }
    float4 v = *(const float4*)(s + (size_t)j * 4);
    ushort4 o;
    o.x = f2bf(v.x); o.y = f2bf(v.y); o.z = f2bf(v.z); o.w = f2bf(v.w);
    *(ushort4*)(d + (size_t)j * 4) = o;
  }
}

// Per-batch compaction scan: keep[l] = (mask[l]==0).
__global__ __launch_bounds__(256) void mask_scan(
    const int* __restrict__ mask, int* __restrict__ idx,
    int* __restrict__ Lc, int* __restrict__ Lcp) {
  const int b = blockIdx.x;
  const int* mb = mask + (size_t)b * 2048;
  int* ib = idx + (size_t)b * 2048;
  const int t = threadIdx.x;
  __shared__ int tot[256];
  __shared__ int off[257];
  int keep[8], cnt = 0;
#pragma unroll
  for (int j = 0; j < 8; ++j) {
    keep[j] = (mb[t * 8 + j] == 0);
    cnt += keep[j];
  }
  tot[t] = cnt;
  __syncthreads();
  if (t == 0) {
    int s = 0;
    for (int i = 0; i < 256; ++i) { off[i] = s; s += tot[i]; }
    off[256] = s;
  }
  __syncthreads();
  int p = off[t];
#pragma unroll
  for (int j = 0; j < 8; ++j)
    if (keep[j]) ib[p++] = t * 8 + j;
  if (t == 0) {
    Lc[b] = off[256];
    Lcp[b] = (off[256] + 127) & ~127;
  }
}

// Gather unmasked H rows (f32) -> Hc (B, L, Dh) bf16 row-major AND
// HcT (B, Dh, L) bf16 transposed. Rows [Lc, Lcp) zero-filled.
__global__ __launch_bounds__(256) void gather_cast(
    const float* __restrict__ H, const int* __restrict__ idx,
    const int* __restrict__ Lc, const int* __restrict__ Lcp,
    unsigned short* __restrict__ Hc, unsigned short* __restrict__ HcT) {
  const int b = blockIdx.z;
  const int j0 = blockIdx.x * 64, d0 = blockIdx.y * 64;
  if (j0 >= Lcp[b]) return;
  const int lc = Lc[b];
  __shared__ unsigned short tile[64][72];
  const int t = threadIdx.x;

  const int r = t >> 2, dc = (t & 3) * 16;
  const int j = j0 + r;
  const int src = (j < lc) ? idx[(size_t)b * 2048 + j] : -1;
  ushort4 s[4];
  if (src >= 0) {
    const float* p = H + ((size_t)b * 2048 + src) * 1024 + d0 + dc;
#pragma unroll
    for (int i = 0; i < 4; ++i) {
      float4 v = *(const float4*)(p + 4 * i);
      s[i].x = f2bf(v.x); s[i].y = f2bf(v.y); s[i].z = f2bf(v.z); s[i].w = f2bf(v.w);
    }
  } else {
#pragma unroll
    for (int i = 0; i < 4; ++i) { s[i].x = 0; s[i].y = 0; s[i].z = 0; s[i].w = 0; }
  }
  unsigned short* hcrow = Hc + ((size_t)b * 2048 + j) * 1024 + d0 + dc;
#pragma unroll
  for (int i = 0; i < 4; ++i) {
    *(ushort4*)&tile[r][dc + 4 * i] = s[i];
    *(ushort4*)(hcrow + 4 * i) = s[i];
  }
  __syncthreads();

  const int dr = t >> 2, lcc = (t & 3) * 16;
  unsigned short o[16];
#pragma unroll
  for (int i = 0; i < 16; ++i) o[i] = tile[lcc + i][dr];
  unsigned short* dst = HcT + ((size_t)b * 1024 + d0 + dr) * 2048 + j0 + lcc;
  *(uint4*)dst = *(uint4*)&o[0];
  *(uint4*)(dst + 8) = *(uint4*)&o[8];
}

// C (M x N tile 128 x BN) = A (M x K) * B^T, bf16 via global_load_lds.
// BK = 64, XOR-swizzled 16B slots (pre-swizzled global source + swizzled read).
// MODE 0: plain 3D grid. MODE 1: batched XCD-chunk swizzle (batch = flat&7).
// MODE 2: single-matrix XCD-chunk swizzle.
// EPI 0: store scale*acc (bf16 or f32).
// EPI 1: store bf16 exp(scale*acc) zeroed at col>=lcArr[b]; emit per-block
//        row sums to Psum[(b*16+bn)*1024 + bm*128 + r] (deterministic).
// EPI 2: store f32 scale*acc*invS[b*1024+row].
template <int BN, bool OUT_BF16, int MODE, int NBN, int EPI>
__global__ __launch_bounds__(256) void gemm_bt(
    const unsigned short* __restrict__ Ag, const unsigned short* __restrict__ Bg,
    void* __restrict__ Cg_, int N, int Kfix, int lda, int ldb, float scale,
    long long strideA, long long strideB, long long strideC,
    const int* __restrict__ mExt, const int* __restrict__ nExt,
    const int* __restrict__ kDyn, const int* __restrict__ lcArr,
    float* __restrict__ Psum, const float* __restrict__ invS) {
  int b, bm, bn;
  if constexpr (MODE == 0) {
    b = blockIdx.z; bm = blockIdx.y; bn = blockIdx.x;
  } else if constexpr (MODE == 1) {
    b = blockIdx.x & 7;
    const int inner = blockIdx.x >> 3;
    bm = inner / NBN; bn = inner % NBN;
  } else {
    const int cs = gridDim.x >> 3;
    const int logical = (blockIdx.x & 7) * cs + (blockIdx.x >> 3);
    b = 0; bm = logical / NBN; bn = logical % NBN;
  }
  if (mExt && bm * 128 >= mExt[b]) return;
  if (nExt && bn * BN >= nExt[b]) return;
  const int K = kDyn ? kDyn[b] : Kfix;

  constexpr int NF = BN / 32;        // B fragments per wave
  __shared__ unsigned short As[128 * 64];
  __shared__ unsigned short Bs[BN * 64];
  __shared__ float psumLds[2][128];  // EPI==1 only (1 KB, harmless otherwise)
  const int tid = threadIdx.x;
  const int l = tid & 63, wid = tid >> 6;
  const int wr = wid >> 1, wc = wid & 1;

  const unsigned short* Abf = Ag + (size_t)b * strideA;
  const unsigned short* Bbf = Bg + (size_t)b * strideB;
  const int rowA0 = bm * 128, rowB0 = bn * BN;

  // Staging lane decode: chunk = 8 rows x 8 slots of 16 B (1 KiB).
  const int srow = l >> 3;                   // row within chunk
  const int sslot = (l & 7) ^ (srow & 7);    // pre-swizzled global 16B slot
  const int soff = sslot * 8;                // shorts

  f32x4 acc[4][NF] = {};

  for (int k0 = 0; k0 < K; k0 += 64) {
    // A: 16 chunks, 4 per wave.
#pragma unroll
    for (int i = 0; i < 4; ++i) {
      const int c = wid * 4 + i;
      gload_lds16(Abf + (size_t)(rowA0 + c * 8 + srow) * lda + k0 + soff,
                  &As[c * 512]);
    }
    // B: BN/8 chunks; 4 per wave (BN=128) or 2 (BN=64).
#pragma unroll
    for (int i = 0; i < BN / 32; ++i) {
      const int c = wid * (BN / 32) + i;
      gload_lds16(Bbf + (size_t)(rowB0 + c * 8 + srow) * ldb + k0 + soff,
                  &Bs[c * 512]);
    }
    __syncthreads();

    s16x8 af[4][2], bfr[NF][2];
#pragma unroll
    for (int m = 0; m < 4; ++m) {
      const int row = wr * 64 + m * 16 + (l & 15);
      const int rx = row & 7;
#pragma unroll
      for (int kk = 0; kk < 2; ++kk) {
        const int slot = kk * 4 + (l >> 4);
        af[m][kk] = *(const s16x8*)&As[row * 64 + (slot ^ rx) * 8];
      }
    }
#pragma unroll
    for (int n = 0; n < NF; ++n) {
      const int row = wc * (BN / 2) + n * 16 + (l & 15);
      const int rx = row & 7;
#pragma unroll
      for (int kk = 0; kk < 2; ++kk) {
        const int slot = kk * 4 + (l >> 4);
        bfr[n][kk] = *(const s16x8*)&Bs[row * 64 + (slot ^ rx) * 8];
      }
    }
#pragma unroll
    for (int kk = 0; kk < 2; ++kk)
#pragma unroll
      for (int m = 0; m < 4; ++m)
#pragma unroll
        for (int n = 0; n < NF; ++n)
          acc[m][n] = __builtin_amdgcn_mfma_f32_16x16x32_bf16(
              af[m][kk], bfr[n][kk], acc[m][n], 0, 0, 0);
    __syncthreads();
  }

  const int crow0 = bm * 128 + wr * 64, ccol0 = bn * BN + wc * (BN / 2);
  unsigned short* Cst = nullptr;
  float* Cf = nullptr;
  if constexpr (OUT_BF16)
    Cst = (unsigned short*)Cg_ + (size_t)b * strideC;
  else
    Cf = (float*)Cg_ + (size_t)b * strideC;

  if constexpr (EPI == 1) {
    const int lcv = lcArr[b];
    float rs[4][4];
#pragma unroll
    for (int m = 0; m < 4; ++m)
#pragma unroll
      for (int r = 0; r < 4; ++r) rs[m][r] = 0.f;
#pragma unroll
    for (int m = 0; m < 4; ++m) {
#pragma unroll
      for (int n = 0; n < NF; ++n) {
#pragma unroll
        for (int r = 0; r < 4; ++r) {
          const int row = crow0 + m * 16 + ((l >> 4) << 2) + r;
          const int col = ccol0 + n * 16 + (l & 15);
          const float e = (col < lcv) ? __expf(acc[m][n][r] * scale) : 0.f;
          rs[m][r] += e;
          Cst[(size_t)row * N + col] = f2bf(e);
        }
      }
    }
    // reduce across the 16 lanes (l&15) sharing each row
#pragma unroll
    for (int m = 0; m < 4; ++m)
#pragma unroll
      for (int r = 0; r < 4; ++r) {
#pragma unroll
        for (int off = 1; off < 16; off <<= 1)
          rs[m][r] += __shfl_xor(rs[m][r], off);
      }
    if ((l & 15) == 0) {
      const int q = l >> 4;
#pragma unroll
      for (int m = 0; m < 4; ++m)
#pragma unroll
        for (int r = 0; r < 4; ++r)
          psumLds[wc][wr * 64 + m * 16 + q * 4 + r] = rs[m][r];
    }
    __syncthreads();
    if (tid < 128)
      Psum[((size_t)b * 16 + bn) * 1024 + bm * 128 + tid] =
          psumLds[0][tid] + psumLds[1][tid];
  } else {
    const float* invb = (EPI == 2) ? (invS + (size_t)b * 1024) : nullptr;
#pragma unroll
    for (int m = 0; m < 4; ++m) {
#pragma unroll
      for (int n = 0; n < NF; ++n) {
#pragma unroll
        for (int r = 0; r < 4; ++r) {
          const int row = crow0 + m * 16 + ((l >> 4) << 2) + r;
          const int col = ccol0 + n * 16 + (l & 15);
          float val = acc[m][n][r] * scale;
          if constexpr (EPI == 2) val *= invb[row];
          if constexpr (OUT_BF16)
            Cst[(size_t)row * N + col] = f2bf(val);
          else
            Cf[(size_t)row * N + col] = val;
        }
      }
    }
  }
}

// invSum[b][row] = 1 / sum_{active bn} Psum[b][bn][row]
__global__ __launch_bounds__(256) void rowsum_inv(
    const float* __restrict__ Psum, const int* __restrict__ Lcp,
    float* __restrict__ invSum) {
  const int i = blockIdx.x * 256 + threadIdx.x;  // 8192 rows total
  const int b = i >> 10, row = i & 1023;
  const int nb = Lcp[b] >> 7;
  float s = 0.f;
  for (int j = 0; j < nb; ++j)
    s += Psum[((size_t)b * 16 + j) * 1024 + row];
  invSum[i] = 1.0f / s;
}

extern "C" void kernel_launch(void* const* d_in, const int* in_sizes, int n_in,
                              void* d_out, int out_size, void* d_ws, size_t ws_size,
                              hipStream_t stream) {
  const float* H  = (const float*)d_in[0];   // (B, L, Dh)
  const float* G  = (const float*)d_in[1];   // (B, T, Dg)
  const int* mask = (const int*)d_in[2];     // (B, L), nonzero = masked
  const float* Wk = (const float*)d_in[3];   // (P, Dh)
  const float* Wq = (const float*)d_in[4];   // (P, Dg)
  float* Z = (float*)d_out;                  // (B, T, Dh)

  const float SCALE = 0.0625f;  // 256^-0.5
  const size_t MiB = 1024 * 1024;

  char* ws = (char*)d_ws;
  unsigned short* HcT  = (unsigned short*)(ws);             // (B, Dh, L)  32 MiB
  unsigned short* Hc   = (unsigned short*)(ws + 32 * MiB);  // (B, L, Dh)  32 MiB
  unsigned short* Sbuf = Hc;  // alias: Hc dead after Kproj; holds P' = exp(S)
  unsigned short* Kc   = (unsigned short*)(ws + 64 * MiB);  // (B, L, P)    8 MiB
  unsigned short* Qbuf = (unsigned short*)(ws + 72 * MiB);  // (B, T, P)    4 MiB
  int* idx = (int*)Qbuf;      // alias: idx dead before Qproj writes
  int* Lc  = (int*)(ws + 76 * MiB);
  int* Lcp = Lc + 16;
  unsigned short* Gbf  = (unsigned short*)(ws + 76 * MiB + 4096);  // 12 MiB
  unsigned short* Wkbf = (unsigned short*)(ws + 89 * MiB);         // 0.5 MiB
  unsigned short* Wqbf = (unsigned short*)(ws + 90 * MiB);         // 0.375 MiB
  float* PsumBuf = (float*)(ws + 91 * MiB);                        // 512 KiB
  float* invSum  = (float*)(ws + 92 * MiB);                        // 32 KiB

  // 0) scan + casts
  mask_scan<<<dim3(8), 256, 0, stream>>>(mask, idx, Lc, Lcp);
  cast3_bf16<<<dim3(1024), 256, 0, stream>>>(
      G, Gbf, 8 * 1024 * 768 / 4, Wk, Wkbf, 256 * 1024 / 4, Wq, Wqbf, 256 * 768 / 4);

  // 1) gather unmasked H rows -> Hc + HcT (bf16), zero pad
  gather_cast<<<dim3(32, 16, 8), 256, 0, stream>>>(H, idx, Lc, Lcp, Hc, HcT);

  // 2) Kc = Hc @ Wk^T  (per batch: M = Lcp[b], N = 256, K = 1024)
  gemm_bt<64, true, 1, 4, 0><<<dim3(512), 256, 0, stream>>>(
      Hc, Wkbf, Kc, 256, 1024, 1024, 1024, 1.0f,
      (long long)2048 * 1024, 0, (long long)2048 * 256,
      Lcp, nullptr, nullptr, nullptr, nullptr, nullptr);

  // 3) Q = G @ Wq^T  (M = 8192, N = 256, K = 768)
  gemm_bt<64, true, 2, 4, 0><<<dim3(256), 256, 0, stream>>>(
      Gbf, Wqbf, Qbuf, 256, 768, 768, 768, 1.0f, 0, 0, 0,
      nullptr, nullptr, nullptr, nullptr, nullptr, nullptr);

  // 4) P' = exp(Q @ Kc^T * SCALE), zeroed at col >= Lc; per-block row sums.
  gemm_bt<128, true, 1, 16, 1><<<dim3(1024), 256, 0, stream>>>(
      Qbuf, Kc, Sbuf, 2048, 256, 256, 256, SCALE,
      (long long)1024 * 256, (long long)2048 * 256, (long long)1024 * 2048,
      nullptr, Lcp, nullptr, Lc, PsumBuf, nullptr);

  // 5) invSum[b][row] = 1 / full row sum
  rowsum_inv<<<dim3(32), 256, 0, stream>>>(PsumBuf, Lcp, invSum);

  // 6) Z = (P' @ Hc) * invSum  (per batch: M = 1024, N = 1024, K = Lcp[b])
  gemm_bt<128, false, 1, 8, 2><<<dim3(512), 256, 0, stream>>>(
      Sbuf, HcT, Z, 1024, 0, 2048, 2048, 1.0f,
      (long long)1024 * 2048, (long long)1024 * 2048, (long long)1024 * 1024,
      nullptr, nullptr, Lcp, nullptr, nullptr, invSum);
}

// Round 10
// 88.483 us; speedup vs baseline: 1.3944x; 1.2498x over previous
//
#include <hip/hip_runtime.h>
#include <hip/hip_bf16.h>

typedef short s16x8 __attribute__((ext_vector_type(8)));
typedef float f32x4 __attribute__((ext_vector_type(4)));
typedef unsigned short u16x8 __attribute__((ext_vector_type(8)));

__device__ __forceinline__ unsigned short f2bf(float f) {
  union { __hip_bfloat16 h; unsigned short u; } cv;
  cv.h = __float2bfloat16(f);
  return cv.u;
}
__device__ __forceinline__ float bf2f(unsigned short u) {
  union { unsigned int i; float f; } cv;
  cv.i = ((unsigned int)u) << 16;
  return cv.f;
}

__device__ __forceinline__ void gload_lds16(const void* g, void* l) {
  __builtin_amdgcn_global_load_lds(
      (const __attribute__((address_space(1))) unsigned int*)g,
      (__attribute__((address_space(3))) unsigned int*)l,
      16, 0, 0);
}

// Merged: blocks [0,1024) cast G/Wk/Wq f32->bf16; blocks [1024,1032) run the
// per-batch mask compaction scan (independent work, one dispatch).
__global__ __launch_bounds__(256) void prep(
    const float* __restrict__ G, unsigned short* __restrict__ Gbf,
    const float* __restrict__ Wk, unsigned short* __restrict__ Wkbf,
    const float* __restrict__ Wq, unsigned short* __restrict__ Wqbf,
    const int* __restrict__ mask, int* __restrict__ idx,
    int* __restrict__ Lc, int* __restrict__ Lcp) {
  const int t = threadIdx.x;
  if (blockIdx.x >= 1024) {
    const int b = blockIdx.x - 1024;
    const int* mb = mask + (size_t)b * 2048;
    int* ib = idx + (size_t)b * 2048;
    __shared__ int tot[256];
    __shared__ int off[257];
    int keep[8], cnt = 0;
#pragma unroll
    for (int j = 0; j < 8; ++j) {
      keep[j] = (mb[t * 8 + j] == 0);
      cnt += keep[j];
    }
    tot[t] = cnt;
    __syncthreads();
    if (t == 0) {
      int s = 0;
      for (int i = 0; i < 256; ++i) { off[i] = s; s += tot[i]; }
      off[256] = s;
    }
    __syncthreads();
    int p = off[t];
#pragma unroll
    for (int j = 0; j < 8; ++j)
      if (keep[j]) ib[p++] = t * 8 + j;
    if (t == 0) {
      Lc[b] = off[256];
      Lcp[b] = (off[256] + 127) & ~127;
    }
    return;
  }
  const int n4a = 8 * 1024 * 768 / 4, n4b = 256 * 1024 / 4, n4c = 256 * 768 / 4;
  const int total = n4a + n4b + n4c;
  for (int i = blockIdx.x * 256 + t; i < total; i += 1024 * 256) {
    const float* s; unsigned short* d; int j = i;
    if (j < n4a) { s = G; d = Gbf; }
    else if ((j -= n4a) < n4b) { s = Wk; d = Wkbf; }
    else { j -= n4b; s = Wq; d = Wqbf; }
    float4 v = *(const float4*)(s + (size_t)j * 4);
    ushort4 o;
    o.x = f2bf(v.x); o.y = f2bf(v.y); o.z = f2bf(v.z); o.w = f2bf(v.w);
    *(ushort4*)(d + (size_t)j * 4) = o;
  }
}

// Gather unmasked H rows (f32) -> Hc (B, L, Dh) bf16 row-major AND
// HcT (B, Dh, L) bf16 transposed. Rows [Lc, Lcp) zero-filled.
__global__ __launch_bounds__(256) void gather_cast(
    const float* __restrict__ H, const int* __restrict__ idx,
    const int* __restrict__ Lc, const int* __restrict__ Lcp,
    unsigned short* __restrict__ Hc, unsigned short* __restrict__ HcT) {
  const int b = blockIdx.z;
  const int j0 = blockIdx.x * 64, d0 = blockIdx.y * 64;
  if (j0 >= Lcp[b]) return;
  const int lc = Lc[b];
  __shared__ unsigned short tile[64][72];
  const int t = threadIdx.x;

  const int r = t >> 2, dc = (t & 3) * 16;
  const int j = j0 + r;
  const int src = (j < lc) ? idx[(size_t)b * 2048 + j] : -1;
  ushort4 s[4];
  if (src >= 0) {
    const float* p = H + ((size_t)b * 2048 + src) * 1024 + d0 + dc;
#pragma unroll
    for (int i = 0; i < 4; ++i) {
      float4 v = *(const float4*)(p + 4 * i);
      s[i].x = f2bf(v.x); s[i].y = f2bf(v.y); s[i].z = f2bf(v.z); s[i].w = f2bf(v.w);
    }
  } else {
#pragma unroll
    for (int i = 0; i < 4; ++i) { s[i].x = 0; s[i].y = 0; s[i].z = 0; s[i].w = 0; }
  }
  unsigned short* hcrow = Hc + ((size_t)b * 2048 + j) * 1024 + d0 + dc;
#pragma unroll
  for (int i = 0; i < 4; ++i) {
    *(ushort4*)&tile[r][dc + 4 * i] = s[i];
    *(ushort4*)(hcrow + 4 * i) = s[i];
  }
  __syncthreads();

  const int dr = t >> 2, lcc = (t & 3) * 16;
  unsigned short o[16];
#pragma unroll
  for (int i = 0; i < 16; ++i) o[i] = tile[lcc + i][dr];
  unsigned short* dst = HcT + ((size_t)b * 1024 + d0 + dr) * 2048 + j0 + lcc;
  *(uint4*)dst = *(uint4*)&o[0];
  *(uint4*)(dst + 8) = *(uint4*)&o[8];
}

// Shared GEMM core: C (128 x BN tile) = A * B^T, bf16 via global_load_lds.
// BK = 64, XOR-swizzled 16B slots (pre-swizzled global source + swizzled read).
// EPI 0: store bf16 scale*acc.
// EPI 1: store bf16 exp(scale*acc), zero at col>=lcv; per-block row sums ->
//        psumOut[0..127] (deterministic).
// EPI 2: f32 store of scale*acc*inv(rowsum); inv computed in prologue from
//        psumB[j*1024 + rowLocal], j<nb.
template <int BN, int EPI, bool OUT_BF16>
__device__ __forceinline__ void gemm_core(
    unsigned short* As, unsigned short* Bs, float* redLds,
    const unsigned short* __restrict__ Abf, const unsigned short* __restrict__ Bbf,
    void* __restrict__ Cg_, int N, int K, int lda, int ldb, float scale,
    int bm, int bn, int lcv, float* __restrict__ psumOut,
    const float* __restrict__ psumB, int nb) {
  constexpr int NF = BN / 32;
  const int tid = threadIdx.x;
  const int l = tid & 63, wid = tid >> 6;
  const int wr = wid >> 1, wc = wid & 1;
  const int rowA0 = bm * 128, rowB0 = bn * BN;

  const int srow = l >> 3;                   // row within 8x8-slot chunk
  const int sslot = (l & 7) ^ (srow & 7);    // pre-swizzled global 16B slot
  const int soff = sslot * 8;

  if constexpr (EPI == 2) {
    if (tid < 128) {
      float s = 0.f;
      for (int j = 0; j < nb; ++j) s += psumB[(size_t)j * 1024 + tid];
      redLds[tid] = 1.0f / s;
    }
  }

  f32x4 acc[4][NF] = {};

  for (int k0 = 0; k0 < K; k0 += 64) {
#pragma unroll
    for (int i = 0; i < 4; ++i) {
      const int c = wid * 4 + i;
      gload_lds16(Abf + (size_t)(rowA0 + c * 8 + srow) * lda + k0 + soff,
                  &As[c * 512]);
    }
#pragma unroll
    for (int i = 0; i < BN / 32; ++i) {
      const int c = wid * (BN / 32) + i;
      gload_lds16(Bbf + (size_t)(rowB0 + c * 8 + srow) * ldb + k0 + soff,
                  &Bs[c * 512]);
    }
    __syncthreads();

    s16x8 af[4][2], bfr[NF][2];
#pragma unroll
    for (int m = 0; m < 4; ++m) {
      const int row = wr * 64 + m * 16 + (l & 15);
      const int rx = row & 7;
#pragma unroll
      for (int kk = 0; kk < 2; ++kk) {
        const int slot = kk * 4 + (l >> 4);
        af[m][kk] = *(const s16x8*)&As[row * 64 + (slot ^ rx) * 8];
      }
    }
#pragma unroll
    for (int n = 0; n < NF; ++n) {
      const int row = wc * (BN / 2) + n * 16 + (l & 15);
      const int rx = row & 7;
#pragma unroll
      for (int kk = 0; kk < 2; ++kk) {
        const int slot = kk * 4 + (l >> 4);
        bfr[n][kk] = *(const s16x8*)&Bs[row * 64 + (slot ^ rx) * 8];
      }
    }
#pragma unroll
    for (int kk = 0; kk < 2; ++kk)
#pragma unroll
      for (int m = 0; m < 4; ++m)
#pragma unroll
        for (int n = 0; n < NF; ++n)
          acc[m][n] = __builtin_amdgcn_mfma_f32_16x16x32_bf16(
              af[m][kk], bfr[n][kk], acc[m][n], 0, 0, 0);
    __syncthreads();
  }

  const int crow0 = bm * 128 + wr * 64, ccol0 = bn * BN + wc * (BN / 2);
  unsigned short* Cst = (unsigned short*)Cg_;
  float* Cf = (float*)Cg_;

  if constexpr (EPI == 1) {
    float (*psumLds)[128] = (float(*)[128])redLds;
    float rs[4][4];
#pragma unroll
    for (int m = 0; m < 4; ++m)
#pragma unroll
      for (int r = 0; r < 4; ++r) rs[m][r] = 0.f;
#pragma unroll
    for (int m = 0; m < 4; ++m) {
#pragma unroll
      for (int n = 0; n < NF; ++n) {
#pragma unroll
        for (int r = 0; r < 4; ++r) {
          const int row = crow0 + m * 16 + ((l >> 4) << 2) + r;
          const int col = ccol0 + n * 16 + (l & 15);
          const float e = (col < lcv) ? __expf(acc[m][n][r] * scale) : 0.f;
          rs[m][r] += e;
          Cst[(size_t)row * N + col] = f2bf(e);
        }
      }
    }
#pragma unroll
    for (int m = 0; m < 4; ++m)
#pragma unroll
      for (int r = 0; r < 4; ++r) {
#pragma unroll
        for (int off = 1; off < 16; off <<= 1)
          rs[m][r] += __shfl_xor(rs[m][r], off);
      }
    if ((l & 15) == 0) {
      const int q = l >> 4;
#pragma unroll
      for (int m = 0; m < 4; ++m)
#pragma unroll
        for (int r = 0; r < 4; ++r)
          psumLds[wc][wr * 64 + m * 16 + q * 4 + r] = rs[m][r];
    }
    __syncthreads();
    if (tid < 128)
      psumOut[tid] = psumLds[0][tid] + psumLds[1][tid];
  } else {
#pragma unroll
    for (int m = 0; m < 4; ++m) {
#pragma unroll
      for (int n = 0; n < NF; ++n) {
#pragma unroll
        for (int r = 0; r < 4; ++r) {
          const int rloc = wr * 64 + m * 16 + ((l >> 4) << 2) + r;
          const int row = bm * 128 + rloc;
          const int col = ccol0 + n * 16 + (l & 15);
          float val = acc[m][n][r] * scale;
          if constexpr (EPI == 2) val *= redLds[rloc];
          if constexpr (OUT_BF16)
            Cst[(size_t)row * N + col] = f2bf(val);
          else
            Cf[(size_t)row * N + col] = val;
        }
      }
    }
  }
}

// Merged K/Q projection: blocks [0,512) Kproj (batched XCD swizzle),
// blocks [512,768) Qproj (single-matrix XCD swizzle). Both 128x64 tiles.
__global__ __launch_bounds__(256) void gemm_kqproj(
    const unsigned short* __restrict__ Hc, const unsigned short* __restrict__ Wkbf,
    unsigned short* __restrict__ Kc,
    const unsigned short* __restrict__ Gbf, const unsigned short* __restrict__ Wqbf,
    unsigned short* __restrict__ Qbuf, const int* __restrict__ Lcp) {
  __shared__ unsigned short As[128 * 64];
  __shared__ unsigned short Bs[64 * 64];
  __shared__ float redLds[256];
  int x = blockIdx.x;
  const unsigned short *A_, *B_;
  unsigned short* C_;
  int K_, ld_, bm, bn;
  if (x < 512) {
    const int b = x & 7, inner = x >> 3;
    bm = inner >> 2; bn = inner & 3;
    if (bm * 128 >= Lcp[b]) return;
    A_ = Hc + (size_t)b * 2048 * 1024;
    B_ = Wkbf;
    C_ = Kc + (size_t)b * 2048 * 256;
    K_ = 1024; ld_ = 1024;
  } else {
    x -= 512;
    const int logical = (x & 7) * 32 + (x >> 3);
    bm = logical >> 2; bn = logical & 3;
    A_ = Gbf; B_ = Wqbf; C_ = Qbuf;
    K_ = 768; ld_ = 768;
  }
  gemm_core<64, 0, true>(As, Bs, redLds, A_, B_, C_, 256, K_, ld_, ld_, 1.0f,
                         bm, bn, 0, nullptr, nullptr, 0);
}

// Score: P' = exp(Q @ Kc^T * SCALE), zeroed at col>=Lc; per-block row sums.
__global__ __launch_bounds__(256) void gemm_score(
    const unsigned short* __restrict__ Qbuf, const unsigned short* __restrict__ Kc,
    unsigned short* __restrict__ Sbuf, const int* __restrict__ Lcp,
    const int* __restrict__ Lc, float* __restrict__ Psum) {
  __shared__ unsigned short As[128 * 64];
  __shared__ unsigned short Bs[128 * 64];
  __shared__ float redLds[256];
  const int b = blockIdx.x & 7, inner = blockIdx.x >> 3;
  const int bm = inner >> 4, bn = inner & 15;
  if (bn * 128 >= Lcp[b]) return;
  gemm_core<128, 1, true>(
      As, Bs, redLds,
      Qbuf + (size_t)b * 1024 * 256, Kc + (size_t)b * 2048 * 256,
      Sbuf + (size_t)b * 1024 * 2048, 2048, 256, 256, 256, 0.0625f,
      bm, bn, Lc[b], Psum + ((size_t)b * 16 + bn) * 1024 + bm * 128,
      nullptr, 0);
}

// PV: Z = (P' @ Hc) * inv(rowsum); inv computed in-block from Psum.
__global__ __launch_bounds__(256) void gemm_pv(
    const unsigned short* __restrict__ Sbuf, const unsigned short* __restrict__ HcT,
    float* __restrict__ Z, const int* __restrict__ Lcp,
    const float* __restrict__ Psum) {
  __shared__ unsigned short As[128 * 64];
  __shared__ unsigned short Bs[128 * 64];
  __shared__ float redLds[256];
  const int b = blockIdx.x & 7, inner = blockIdx.x >> 3;
  const int bm = inner >> 3, bn = inner & 7;
  const int K = Lcp[b], nb = K >> 7;
  gemm_core<128, 2, false>(
      As, Bs, redLds,
      Sbuf + (size_t)b * 1024 * 2048, HcT + (size_t)b * 1024 * 2048,
      Z + (size_t)b * 1024 * 1024, 1024, K, 2048, 2048, 1.0f,
      bm, bn, 0, nullptr, Psum + (size_t)b * 16 * 1024 + bm * 128, nb);
}

extern "C" void kernel_launch(void* const* d_in, const int* in_sizes, int n_in,
                              void* d_out, int out_size, void* d_ws, size_t ws_size,
                              hipStream_t stream) {
  const float* H  = (const float*)d_in[0];   // (B, L, Dh)
  const float* G  = (const float*)d_in[1];   // (B, T, Dg)
  const int* mask = (const int*)d_in[2];     // (B, L), nonzero = masked
  const float* Wk = (const float*)d_in[3];   // (P, Dh)
  const float* Wq = (const float*)d_in[4];   // (P, Dg)
  float* Z = (float*)d_out;                  // (B, T, Dh)

  const size_t MiB = 1024 * 1024;
  char* ws = (char*)d_ws;
  unsigned short* HcT  = (unsigned short*)(ws);             // (B, Dh, L)  32 MiB
  unsigned short* Hc   = (unsigned short*)(ws + 32 * MiB);  // (B, L, Dh)  32 MiB
  unsigned short* Sbuf = Hc;  // alias: Hc dead after Kproj; holds P' = exp(S)
  unsigned short* Kc   = (unsigned short*)(ws + 64 * MiB);  // (B, L, P)    8 MiB
  unsigned short* Qbuf = (unsigned short*)(ws + 72 * MiB);  // (B, T, P)    4 MiB
  int* idx = (int*)Qbuf;      // alias: idx dead (after gather) before Qproj writes
  int* Lc  = (int*)(ws + 76 * MiB);
  int* Lcp = Lc + 16;
  unsigned short* Gbf  = (unsigned short*)(ws + 76 * MiB + 4096);  // 12 MiB
  unsigned short* Wkbf = (unsigned short*)(ws + 89 * MiB);         // 0.5 MiB
  unsigned short* Wqbf = (unsigned short*)(ws + 90 * MiB);         // 0.375 MiB
  float* PsumBuf = (float*)(ws + 91 * MiB);                        // 512 KiB

  // 1) casts (G, Wk, Wq) + mask scan in one dispatch
  prep<<<dim3(1032), 256, 0, stream>>>(G, Gbf, Wk, Wkbf, Wq, Wqbf,
                                       mask, idx, Lc, Lcp);

  // 2) gather unmasked H rows -> Hc + HcT (bf16), zero pad
  gather_cast<<<dim3(32, 16, 8), 256, 0, stream>>>(H, idx, Lc, Lcp, Hc, HcT);

  // 3) Kc = Hc @ Wk^T  and  Q = G @ Wq^T, one dispatch (768 blocks)
  gemm_kqproj<<<dim3(768), 256, 0, stream>>>(Hc, Wkbf, Kc, Gbf, Wqbf, Qbuf, Lcp);

  // 4) P' = exp(Q @ Kc^T * SCALE) + per-block row sums
  gemm_score<<<dim3(1024), 256, 0, stream>>>(Qbuf, Kc, Sbuf, Lcp, Lc, PsumBuf);

  // 5) Z = (P' @ Hc) * invRowSum  (inv folded into PV prologue)
  gemm_pv<<<dim3(512), 256, 0, stream>>>(Sbuf, HcT, Z, Lcp, PsumBuf);
}

// Round 11
// 85.168 us; speedup vs baseline: 1.4487x; 1.0389x over previous
//
#include <hip/hip_runtime.h>
#include <hip/hip_bf16.h>

typedef short s16x8 __attribute__((ext_vector_type(8)));
typedef float f32x4 __attribute__((ext_vector_type(4)));
typedef unsigned short u16x8 __attribute__((ext_vector_type(8)));

__device__ __forceinline__ unsigned short f2bf(float f) {
  union { __hip_bfloat16 h; unsigned short u; } cv;
  cv.h = __float2bfloat16(f);
  return cv.u;
}
__device__ __forceinline__ float bf2f(unsigned short u) {
  union { unsigned int i; float f; } cv;
  cv.i = ((unsigned int)u) << 16;
  return cv.f;
}

__device__ __forceinline__ void gload_lds16(const void* g, void* l) {
  __builtin_amdgcn_global_load_lds(
      (const __attribute__((address_space(1))) unsigned int*)g,
      (__attribute__((address_space(3))) unsigned int*)l,
      16, 0, 0);
}

// Parallel exclusive scan of per-thread counts over 256 threads.
// Returns exclusive offset; *total gets the block-wide sum.
__device__ __forceinline__ int block_excl_scan(int cnt, int* wsum, int* total) {
  const int t = threadIdx.x;
  const int lane = t & 63, w = t >> 6;
  int x = cnt;
#pragma unroll
  for (int d = 1; d < 64; d <<= 1) {
    int y = __shfl_up(x, d);
    if (lane >= d) x += y;
  }
  if (lane == 63) wsum[w] = x;
  __syncthreads();
  int woff = 0;
#pragma unroll
  for (int i = 0; i < 4; ++i)
    if (i < w) woff += wsum[i];
  *total = wsum[0] + wsum[1] + wsum[2] + wsum[3];
  return woff + x - cnt;  // exclusive offset
}

// Fused: blocks [0,4096) gather H rows (local mask scan per block);
// blocks [4096,4104) write Lc/Lcp; blocks [4104,5128) cast G/Wk/Wq.
__global__ __launch_bounds__(256) void prep_gather(
    const float* __restrict__ H, const int* __restrict__ mask,
    int* __restrict__ Lc, int* __restrict__ Lcp,
    unsigned short* __restrict__ Hc, unsigned short* __restrict__ HcT,
    const float* __restrict__ G, unsigned short* __restrict__ Gbf,
    const float* __restrict__ Wk, unsigned short* __restrict__ Wkbf,
    const float* __restrict__ Wq, unsigned short* __restrict__ Wqbf) {
  const int t = threadIdx.x;
  const int flat = blockIdx.x;

  if (flat >= 4104) {  // ---- cast blocks ----
    const int cb = flat - 4104;
    const int n4a = 8 * 1024 * 768 / 4, n4b = 256 * 1024 / 4, n4c = 256 * 768 / 4;
    const int total = n4a + n4b + n4c;
    for (int i = cb * 256 + t; i < total; i += 1024 * 256) {
      const float* s; unsigned short* d; int j = i;
      if (j < n4a) { s = G; d = Gbf; }
      else if ((j -= n4a) < n4b) { s = Wk; d = Wkbf; }
      else { j -= n4b; s = Wq; d = Wqbf; }
      float4 v = *(const float4*)(s + (size_t)j * 4);
      ushort4 o;
      o.x = f2bf(v.x); o.y = f2bf(v.y); o.z = f2bf(v.z); o.w = f2bf(v.w);
      *(ushort4*)(d + (size_t)j * 4) = o;
    }
    return;
  }

  __shared__ int wsum[4];

  if (flat >= 4096) {  // ---- Lc/Lcp writeout blocks ----
    const int b = flat - 4096;
    const int* mb = mask + (size_t)b * 2048;
    int cnt = 0;
#pragma unroll
    for (int j = 0; j < 8; ++j) cnt += (mb[t * 8 + j] == 0);
    int total;
    block_excl_scan(cnt, wsum, &total);
    if (t == 0) {
      Lc[b] = total;
      Lcp[b] = (total + 127) & ~127;
    }
    return;
  }

  // ---- gather blocks: b XCD-spread, 512 per batch ----
  const int b = flat & 7;
  const int inner = flat >> 3;
  const int j0 = (inner & 31) * 64, d0 = (inner >> 5) * 64;

  // local mask scan -> lidx[64] (compacted source rows for [j0, j0+64))
  const int* mb = mask + (size_t)b * 2048;
  int keep[8], cnt = 0;
#pragma unroll
  for (int j = 0; j < 8; ++j) {
    keep[j] = (mb[t * 8 + j] == 0);
    cnt += keep[j];
  }
  int total;
  int p = block_excl_scan(cnt, wsum, &total);
  const int lcp = (total + 127) & ~127;
  if (j0 >= lcp) return;
  const int lc = total;

  __shared__ int lidx[64];
#pragma unroll
  for (int j = 0; j < 8; ++j) {
    if (keep[j]) {
      if (p >= j0 && p < j0 + 64) lidx[p - j0] = t * 8 + j;
      ++p;
    }
  }
  __shared__ unsigned short tile[64][72];
  __syncthreads();

  const int r = t >> 2, dc = (t & 3) * 16;
  const int j = j0 + r;
  const int src = (j < lc) ? lidx[r] : -1;
  ushort4 s[4];
  if (src >= 0) {
    const float* pp = H + ((size_t)b * 2048 + src) * 1024 + d0 + dc;
#pragma unroll
    for (int i = 0; i < 4; ++i) {
      float4 v = *(const float4*)(pp + 4 * i);
      s[i].x = f2bf(v.x); s[i].y = f2bf(v.y); s[i].z = f2bf(v.z); s[i].w = f2bf(v.w);
    }
  } else {
#pragma unroll
    for (int i = 0; i < 4; ++i) { s[i].x = 0; s[i].y = 0; s[i].z = 0; s[i].w = 0; }
  }
  unsigned short* hcrow = Hc + ((size_t)b * 2048 + j) * 1024 + d0 + dc;
#pragma unroll
  for (int i = 0; i < 4; ++i) {
    *(ushort4*)&tile[r][dc + 4 * i] = s[i];
    *(ushort4*)(hcrow + 4 * i) = s[i];
  }
  __syncthreads();

  const int dr = t >> 2, lcc = (t & 3) * 16;
  unsigned short o[16];
#pragma unroll
  for (int i = 0; i < 16; ++i) o[i] = tile[lcc + i][dr];
  unsigned short* dst = HcT + ((size_t)b * 1024 + d0 + dr) * 2048 + j0 + lcc;
  *(uint4*)dst = *(uint4*)&o[0];
  *(uint4*)(dst + 8) = *(uint4*)&o[8];
}

// Shared GEMM core: C (128 x BN tile) = A * B^T, bf16 via global_load_lds.
// BK = 64, XOR-swizzled 16B slots (pre-swizzled global source + swizzled read).
// EPI 0: store bf16 scale*acc.
// EPI 1: store bf16 exp(scale*acc), zero at col>=lcv; per-block row sums ->
//        psumOut[0..127] (deterministic).
// EPI 2: f32 store of scale*acc*inv(rowsum); inv computed in prologue from
//        psumB[j*1024 + rowLocal], j<nb.
template <int BN, int EPI, bool OUT_BF16>
__device__ __forceinline__ void gemm_core(
    unsigned short* As, unsigned short* Bs, float* redLds,
    const unsigned short* __restrict__ Abf, const unsigned short* __restrict__ Bbf,
    void* __restrict__ Cg_, int N, int K, int lda, int ldb, float scale,
    int bm, int bn, int lcv, float* __restrict__ psumOut,
    const float* __restrict__ psumB, int nb) {
  constexpr int NF = BN / 32;
  const int tid = threadIdx.x;
  const int l = tid & 63, wid = tid >> 6;
  const int wr = wid >> 1, wc = wid & 1;
  const int rowA0 = bm * 128, rowB0 = bn * BN;

  const int srow = l >> 3;                   // row within 8x8-slot chunk
  const int sslot = (l & 7) ^ (srow & 7);    // pre-swizzled global 16B slot
  const int soff = sslot * 8;

  if constexpr (EPI == 2) {
    if (tid < 128) {
      float s = 0.f;
      for (int j = 0; j < nb; ++j) s += psumB[(size_t)j * 1024 + tid];
      redLds[tid] = 1.0f / s;
    }
  }

  f32x4 acc[4][NF] = {};

  for (int k0 = 0; k0 < K; k0 += 64) {
#pragma unroll
    for (int i = 0; i < 4; ++i) {
      const int c = wid * 4 + i;
      gload_lds16(Abf + (size_t)(rowA0 + c * 8 + srow) * lda + k0 + soff,
                  &As[c * 512]);
    }
#pragma unroll
    for (int i = 0; i < BN / 32; ++i) {
      const int c = wid * (BN / 32) + i;
      gload_lds16(Bbf + (size_t)(rowB0 + c * 8 + srow) * ldb + k0 + soff,
                  &Bs[c * 512]);
    }
    __syncthreads();

    s16x8 af[4][2], bfr[NF][2];
#pragma unroll
    for (int m = 0; m < 4; ++m) {
      const int row = wr * 64 + m * 16 + (l & 15);
      const int rx = row & 7;
#pragma unroll
      for (int kk = 0; kk < 2; ++kk) {
        const int slot = kk * 4 + (l >> 4);
        af[m][kk] = *(const s16x8*)&As[row * 64 + (slot ^ rx) * 8];
      }
    }
#pragma unroll
    for (int n = 0; n < NF; ++n) {
      const int row = wc * (BN / 2) + n * 16 + (l & 15);
      const int rx = row & 7;
#pragma unroll
      for (int kk = 0; kk < 2; ++kk) {
        const int slot = kk * 4 + (l >> 4);
        bfr[n][kk] = *(const s16x8*)&Bs[row * 64 + (slot ^ rx) * 8];
      }
    }
#pragma unroll
    for (int kk = 0; kk < 2; ++kk)
#pragma unroll
      for (int m = 0; m < 4; ++m)
#pragma unroll
        for (int n = 0; n < NF; ++n)
          acc[m][n] = __builtin_amdgcn_mfma_f32_16x16x32_bf16(
              af[m][kk], bfr[n][kk], acc[m][n], 0, 0, 0);
    __syncthreads();
  }

  const int crow0 = bm * 128 + wr * 64, ccol0 = bn * BN + wc * (BN / 2);
  unsigned short* Cst = (unsigned short*)Cg_;
  float* Cf = (float*)Cg_;

  if constexpr (EPI == 1) {
    float (*psumLds)[128] = (float(*)[128])redLds;
    float rs[4][4];
#pragma unroll
    for (int m = 0; m < 4; ++m)
#pragma unroll
      for (int r = 0; r < 4; ++r) rs[m][r] = 0.f;
#pragma unroll
    for (int m = 0; m < 4; ++m) {
#pragma unroll
      for (int n = 0; n < NF; ++n) {
#pragma unroll
        for (int r = 0; r < 4; ++r) {
          const int row = crow0 + m * 16 + ((l >> 4) << 2) + r;
          const int col = ccol0 + n * 16 + (l & 15);
          const float e = (col < lcv) ? __expf(acc[m][n][r] * scale) : 0.f;
          rs[m][r] += e;
          Cst[(size_t)row * N + col] = f2bf(e);
        }
      }
    }
#pragma unroll
    for (int m = 0; m < 4; ++m)
#pragma unroll
      for (int r = 0; r < 4; ++r) {
#pragma unroll
        for (int off = 1; off < 16; off <<= 1)
          rs[m][r] += __shfl_xor(rs[m][r], off);
      }
    if ((l & 15) == 0) {
      const int q = l >> 4;
#pragma unroll
      for (int m = 0; m < 4; ++m)
#pragma unroll
        for (int r = 0; r < 4; ++r)
          psumLds[wc][wr * 64 + m * 16 + q * 4 + r] = rs[m][r];
    }
    __syncthreads();
    if (tid < 128)
      psumOut[tid] = psumLds[0][tid] + psumLds[1][tid];
  } else {
#pragma unroll
    for (int m = 0; m < 4; ++m) {
#pragma unroll
      for (int n = 0; n < NF; ++n) {
#pragma unroll
        for (int r = 0; r < 4; ++r) {
          const int rloc = wr * 64 + m * 16 + ((l >> 4) << 2) + r;
          const int row = bm * 128 + rloc;
          const int col = ccol0 + n * 16 + (l & 15);
          float val = acc[m][n][r] * scale;
          if constexpr (EPI == 2) val *= redLds[rloc];
          if constexpr (OUT_BF16)
            Cst[(size_t)row * N + col] = f2bf(val);
          else
            Cf[(size_t)row * N + col] = val;
        }
      }
    }
  }
}

// Merged K/Q projection: blocks [0,512) Kproj (batched XCD swizzle),
// blocks [512,768) Qproj (single-matrix XCD swizzle). Both 128x64 tiles.
__global__ __launch_bounds__(256) void gemm_kqproj(
    const unsigned short* __restrict__ Hc, const unsigned short* __restrict__ Wkbf,
    unsigned short* __restrict__ Kc,
    const unsigned short* __restrict__ Gbf, const unsigned short* __restrict__ Wqbf,
    unsigned short* __restrict__ Qbuf, const int* __restrict__ Lcp) {
  __shared__ unsigned short As[128 * 64];
  __shared__ unsigned short Bs[64 * 64];
  __shared__ float redLds[256];
  int x = blockIdx.x;
  const unsigned short *A_, *B_;
  unsigned short* C_;
  int K_, ld_, bm, bn;
  if (x < 512) {
    const int b = x & 7, inner = x >> 3;
    bm = inner >> 2; bn = inner & 3;
    if (bm * 128 >= Lcp[b]) return;
    A_ = Hc + (size_t)b * 2048 * 1024;
    B_ = Wkbf;
    C_ = Kc + (size_t)b * 2048 * 256;
    K_ = 1024; ld_ = 1024;
  } else {
    x -= 512;
    const int logical = (x & 7) * 32 + (x >> 3);
    bm = logical >> 2; bn = logical & 3;
    A_ = Gbf; B_ = Wqbf; C_ = Qbuf;
    K_ = 768; ld_ = 768;
  }
  gemm_core<64, 0, true>(As, Bs, redLds, A_, B_, C_, 256, K_, ld_, ld_, 1.0f,
                         bm, bn, 0, nullptr, nullptr, 0);
}

// Score: P' = exp(Q @ Kc^T * SCALE), zeroed at col>=Lc; per-block row sums.
__global__ __launch_bounds__(256) void gemm_score(
    const unsigned short* __restrict__ Qbuf, const unsigned short* __restrict__ Kc,
    unsigned short* __restrict__ Sbuf, const int* __restrict__ Lcp,
    const int* __restrict__ Lc, float* __restrict__ Psum) {
  __shared__ unsigned short As[128 * 64];
  __shared__ unsigned short Bs[128 * 64];
  __shared__ float redLds[256];
  const int b = blockIdx.x & 7, inner = blockIdx.x >> 3;
  const int bm = inner >> 4, bn = inner & 15;
  if (bn * 128 >= Lcp[b]) return;
  gemm_core<128, 1, true>(
      As, Bs, redLds,
      Qbuf + (size_t)b * 1024 * 256, Kc + (size_t)b * 2048 * 256,
      Sbuf + (size_t)b * 1024 * 2048, 2048, 256, 256, 256, 0.0625f,
      bm, bn, Lc[b], Psum + ((size_t)b * 16 + bn) * 1024 + bm * 128,
      nullptr, 0);
}

// PV: Z = (P' @ Hc) * inv(rowsum); inv computed in-block from Psum.
__global__ __launch_bounds__(256) void gemm_pv(
    const unsigned short* __restrict__ Sbuf, const unsigned short* __restrict__ HcT,
    float* __restrict__ Z, const int* __restrict__ Lcp,
    const float* __restrict__ Psum) {
  __shared__ unsigned short As[128 * 64];
  __shared__ unsigned short Bs[128 * 64];
  __shared__ float redLds[256];
  const int b = blockIdx.x & 7, inner = blockIdx.x >> 3;
  const int bm = inner >> 3, bn = inner & 7;
  const int K = Lcp[b], nb = K >> 7;
  gemm_core<128, 2, false>(
      As, Bs, redLds,
      Sbuf + (size_t)b * 1024 * 2048, HcT + (size_t)b * 1024 * 2048,
      Z + (size_t)b * 1024 * 1024, 1024, K, 2048, 2048, 1.0f,
      bm, bn, 0, nullptr, Psum + (size_t)b * 16 * 1024 + bm * 128, nb);
}

extern "C" void kernel_launch(void* const* d_in, const int* in_sizes, int n_in,
                              void* d_out, int out_size, void* d_ws, size_t ws_size,
                              hipStream_t stream) {
  const float* H  = (const float*)d_in[0];   // (B, L, Dh)
  const float* G  = (const float*)d_in[1];   // (B, T, Dg)
  const int* mask = (const int*)d_in[2];     // (B, L), nonzero = masked
  const float* Wk = (const float*)d_in[3];   // (P, Dh)
  const float* Wq = (const float*)d_in[4];   // (P, Dg)
  float* Z = (float*)d_out;                  // (B, T, Dh)

  const size_t MiB = 1024 * 1024;
  char* ws = (char*)d_ws;
  unsigned short* HcT  = (unsigned short*)(ws);             // (B, Dh, L)  32 MiB
  unsigned short* Hc   = (unsigned short*)(ws + 32 * MiB);  // (B, L, Dh)  32 MiB
  unsigned short* Sbuf = Hc;  // alias: Hc dead after Kproj; holds P' = exp(S)
  unsigned short* Kc   = (unsigned short*)(ws + 64 * MiB);  // (B, L, P)    8 MiB
  unsigned short* Qbuf = (unsigned short*)(ws + 72 * MiB);  // (B, T, P)    4 MiB
  int* Lc  = (int*)(ws + 76 * MiB);
  int* Lcp = Lc + 16;
  unsigned short* Gbf  = (unsigned short*)(ws + 76 * MiB + 4096);  // 12 MiB
  unsigned short* Wkbf = (unsigned short*)(ws + 89 * MiB);         // 0.5 MiB
  unsigned short* Wqbf = (unsigned short*)(ws + 90 * MiB);         // 0.375 MiB
  float* PsumBuf = (float*)(ws + 91 * MiB);                        // 512 KiB

  // 1) fused: gather (local scans) + Lc/Lcp writeout + casts, one dispatch
  prep_gather<<<dim3(5128), 256, 0, stream>>>(
      H, mask, Lc, Lcp, Hc, HcT, G, Gbf, Wk, Wkbf, Wq, Wqbf);

  // 2) Kc = Hc @ Wk^T  and  Q = G @ Wq^T, one dispatch (768 blocks)
  gemm_kqproj<<<dim3(768), 256, 0, stream>>>(Hc, Wkbf, Kc, Gbf, Wqbf, Qbuf, Lcp);

  // 3) P' = exp(Q @ Kc^T * SCALE) + per-block row sums
  gemm_score<<<dim3(1024), 256, 0, stream>>>(Qbuf, Kc, Sbuf, Lcp, Lc, PsumBuf);

  // 4) Z = (P' @ Hc) * invRowSum  (inv folded into PV prologue)
  gemm_pv<<<dim3(512), 256, 0, stream>>>(Sbuf, HcT, Z, Lcp, PsumBuf);
}